// Round 17
// baseline (115.837 us; speedup 1.0000x reference)
//
#include <hip/hip_runtime.h>

#define NG   2000
#define NPG  50
#define EPG  800
#define F0   64
#define FH   128
#define FP   512

typedef __attribute__((ext_vector_type(8))) short  short8;
typedef __attribute__((ext_vector_type(8))) __bf16 bf16x8;
typedef __attribute__((ext_vector_type(4))) float  f32x4;
typedef unsigned short u16;
typedef unsigned int   u32;

__device__ inline u16 bf16_rne(float x) {
    u32 u = __builtin_bit_cast(u32, x);
    u += 0x7fffu + ((u >> 16) & 1u);
    return (u16)(u >> 16);
}
__device__ inline float bf16f(u16 h) {
    u32 u = ((u32)h) << 16;
    return __builtin_bit_cast(float, u);
}
// dst.b16[0] = bf16(src0), dst.b16[1] = bf16(src1)
__device__ inline u32 cvtpk2(float lo, float hi) {
    u32 r;
    asm("v_cvt_pk_bf16_f32 %0, %1, %2" : "=v"(r) : "v"(lo), "v"(hi));
    return r;
}
__device__ inline void split2(float v0, float v1, u32& hp, u32& lp) {
    hp = cvtpk2(v0, v1);
    float h0 = __builtin_bit_cast(float, hp << 16);
    float h1 = __builtin_bit_cast(float, hp & 0xffff0000u);
    lp = cvtpk2(v0 - h0, v1 - h1);
}
__device__ inline f32x4 mfma16(short8 a, short8 b, f32x4 c) {
    return __builtin_amdgcn_mfma_f32_16x16x32_bf16(
        __builtin_bit_cast(bf16x8, a), __builtin_bit_cast(bf16x8, b), c, 0, 0, 0);
}

// swizzled index helpers
__device__ inline int xb_idx(int row, int col) { return row * 128 + (col ^ ((row & 7) << 3)); } // u16 units
__device__ inline int cn_idx(int d, int s)     { return d * 64  + (s   ^ ((d   & 7) << 3)); }   // f32 units

// ---------- one-time W split+pack into MFMA B-fragment layout ----------
__global__ __launch_bounds__(256) void pack_w(
    const float* __restrict__ W0, const float* __restrict__ W1,
    const float* __restrict__ W2, u16* __restrict__ WpH, u16* __restrict__ WpL)
{
    int t = blockIdx.x * 256 + threadIdx.x;
    if (t >= 80 * 64) return;
    int fid = t >> 6, lane = t & 63;
    const float* W; int nsub, kstep;
    if (fid < 16)      { W = W0; int r = fid;      nsub = r >> 1; kstep = r & 1; }
    else if (fid < 48) { W = W1; int r = fid - 16; nsub = r >> 2; kstep = r & 3; }
    else               { W = W2; int r = fid - 48; nsub = r >> 2; kstep = r & 3; }
    int n  = nsub * 16 + (lane & 15);
    int kb = kstep * 32 + (lane >> 4) * 8;
    size_t off = (size_t)fid * 512 + (size_t)lane * 8;
#pragma unroll
    for (int i = 0; i < 8; ++i) {
        float v = W[(size_t)(kb + i) * FH + n];
        u16 h = bf16_rne(v);
        WpH[off + i] = h;
        WpL[off + i] = bf16_rne(v - bf16f(h));
    }
}

// ---------- fused layer: mfma1 (T in regs) -> lane-shuffle -> mfma2 ----------
// wave = nsg owns feats [16*nsg, 16*nsg+16) through the whole layer.
template<int KST, bool LAST>
__device__ void layer_fn(const u16* __restrict__ WpH, const u16* __restrict__ WpL,
                         int fid0, const float* __restrict__ bias,
                         u16* XbH, u16* XbL,
                         const short8 (&aReg)[4][2],
                         float* pool, const float* nin64, const float* nout64,
                         int lane, int nsg)
{
    const int l15 = lane & 15, lk = lane >> 4;
    const int feat = nsg * 16 + l15;
    const float bc = bias[feat];

    // --- mfma1: T = (X @ W) * nout. ks-outer: only one W frag pair live (8 regs);
    //     4 independent acc chains (AGPR-eligible) -> low arch-VGPR pressure.
    f32x4 acc[4];
#pragma unroll
    for (int ms = 0; ms < 4; ++ms) acc[ms] = f32x4{0.f, 0.f, 0.f, 0.f};
#pragma unroll
    for (int ks = 0; ks < KST; ++ks) {
        size_t off = (size_t)(fid0 + nsg * KST + ks) * 512 + (size_t)lane * 8;
        short8 wwh = *(const short8*)(WpH + off);
        short8 wwl = *(const short8*)(WpL + off);
        const int c0 = ks * 32 + lk * 8;
#pragma unroll
        for (int ms = 0; ms < 4; ++ms) {
            const int arow = ms * 16 + l15;
            short8 xh = *(const short8*)&XbH[xb_idx(arow, c0)];
            short8 xl = *(const short8*)&XbL[xb_idx(arow, c0)];
            acc[ms] = mfma16(xh, wwh, acc[ms]);
            acc[ms] = mfma16(xh, wwl, acc[ms]);
            acc[ms] = mfma16(xl, wwh, acc[ms]);
        }
    }
    u32 Th01[4], Th23[4], Tl01[4], Tl23[4];
#pragma unroll
    for (int ms = 0; ms < 4; ++ms) {
        const int nb = ms * 16 + lk * 4;
        float4 nq = *(const float4*)&nout64[nb];   // 0 for nodes >= NPG
        split2(acc[ms][0] * nq.x, acc[ms][1] * nq.y, Th01[ms], Tl01[ms]);
        split2(acc[ms][2] * nq.z, acc[ms][3] * nq.w, Th23[ms], Tl23[ms]);
    }

    // --- in-wave redistribution: D-layout -> B-fragments (l15 preserved) ---
    // target (lk,i): node = ks*32+lk*8+i; src lane lk_s=(2lk+(i>>2))&3; ms=2ks+(lk>>1)
    const int srcA = (((lk << 1) & 3) << 4) | l15;
    const int srcB = srcA + 16;
    const bool hiMs = (lk & 2) != 0;
    short8 sbh[2], sbl[2];
#pragma unroll
    for (int ks = 0; ks < 2; ++ks) {
        u32 q0a = __shfl((int)Th01[2 * ks], srcA, 64), q0b = __shfl((int)Th01[2 * ks + 1], srcA, 64);
        u32 q1a = __shfl((int)Th23[2 * ks], srcA, 64), q1b = __shfl((int)Th23[2 * ks + 1], srcA, 64);
        u32 q2a = __shfl((int)Th01[2 * ks], srcB, 64), q2b = __shfl((int)Th01[2 * ks + 1], srcB, 64);
        u32 q3a = __shfl((int)Th23[2 * ks], srcB, 64), q3b = __shfl((int)Th23[2 * ks + 1], srcB, 64);
        uint4 qh = make_uint4(hiMs ? q0b : q0a, hiMs ? q1b : q1a,
                              hiMs ? q2b : q2a, hiMs ? q3b : q3a);
        u32 p0a = __shfl((int)Tl01[2 * ks], srcA, 64), p0b = __shfl((int)Tl01[2 * ks + 1], srcA, 64);
        u32 p1a = __shfl((int)Tl23[2 * ks], srcA, 64), p1b = __shfl((int)Tl23[2 * ks + 1], srcA, 64);
        u32 p2a = __shfl((int)Tl01[2 * ks], srcB, 64), p2b = __shfl((int)Tl01[2 * ks + 1], srcB, 64);
        u32 p3a = __shfl((int)Tl23[2 * ks], srcB, 64), p3b = __shfl((int)Tl23[2 * ks + 1], srcB, 64);
        uint4 ql = make_uint4(hiMs ? p0b : p0a, hiMs ? p1b : p1a,
                              hiMs ? p2b : p2a, hiMs ? p3b : p3a);
        sbh[ks] = __builtin_bit_cast(short8, qh);
        sbl[ks] = __builtin_bit_cast(short8, ql);
    }

    __syncthreads();   // all Xb reads done before mfma2 overwrites Xb

    // --- mfma2: X' = relu((C @ T) * nin + b) ---
    float vs = 0.f;
#pragma unroll
    for (int ms = 0; ms < 4; ++ms) {
        f32x4 p0 = {0.f, 0.f, 0.f, 0.f}, p1 = p0;
        p0 = mfma16(aReg[ms][0], sbh[0], p0);
        p1 = mfma16(aReg[ms][1], sbh[1], p1);
        p0 = mfma16(aReg[ms][0], sbl[0], p0);
        p1 = mfma16(aReg[ms][1], sbl[1], p1);
        f32x4 a2 = p0 + p1;
        const int nb = ms * 16 + lk * 4;
        float4 ninq = *(const float4*)&nin64[nb];
        float v0 = (nb + 0 < NPG) ? fmaxf(fmaf(a2[0], ninq.x, bc), 0.f) : 0.f;
        float v1 = (nb + 1 < NPG) ? fmaxf(fmaf(a2[1], ninq.y, bc), 0.f) : 0.f;
        float v2 = (nb + 2 < NPG) ? fmaxf(fmaf(a2[2], ninq.z, bc), 0.f) : 0.f;
        float v3 = (nb + 3 < NPG) ? fmaxf(fmaf(a2[3], ninq.w, bc), 0.f) : 0.f;
        if (LAST) {
            vs += v0 + v1 + v2 + v3;
        } else {
            u32 hp01, lp01, hp23, lp23;
            split2(v0, v1, hp01, lp01);
            split2(v2, v3, hp23, lp23);
            XbH[xb_idx(nb + 0, feat)] = (u16)hp01;
            XbH[xb_idx(nb + 1, feat)] = (u16)(hp01 >> 16);
            XbH[xb_idx(nb + 2, feat)] = (u16)hp23;
            XbH[xb_idx(nb + 3, feat)] = (u16)(hp23 >> 16);
            XbL[xb_idx(nb + 0, feat)] = (u16)lp01;
            XbL[xb_idx(nb + 1, feat)] = (u16)(lp01 >> 16);
            XbL[xb_idx(nb + 2, feat)] = (u16)lp23;
            XbL[xb_idx(nb + 3, feat)] = (u16)(lp23 >> 16);
        }
    }
    if (LAST) {
        vs += __shfl_xor(vs, 16, 64);
        vs += __shfl_xor(vs, 32, 64);
        if (lane < 16) pool[feat] = vs;   // wave-exclusive feats: plain store
    }
}

// ---------- main fused kernel: one block = one graph, 3 blocks/CU target ----------
__global__ __launch_bounds__(512, 6) void gcn_fused(
    const float* __restrict__ nf, const int* __restrict__ pair,
    const float* __restrict__ b0, const float* __restrict__ b1,
    const float* __restrict__ b2,
    const u16* __restrict__ WpH, const u16* __restrict__ WpL,
    float* __restrict__ means)
{
    __shared__ u16   XbH[64 * 128], XbL[64 * 128];  // X hi/lo [node][feat], swizzled
    __shared__ float cnt[NPG * 64];                 // exact edge counts (f32), swizzled
    __shared__ float pool[FH];
    __shared__ float nin64[64], nout64[64];

    const int tid  = threadIdx.x;
    const int g    = blockIdx.x;
    const int base = g * NPG, ebase = g * EPG;
    const int* srcp = pair;
    const int* dstp = pair + (size_t)NG * EPG;

    // ---- init ----
    for (int i = tid; i < NPG * 64; i += 512) cnt[i] = 0.f;
    for (int i = 3200 + tid; i < 4096; i += 512) {   // Xb pad rows 50-63
        ((u32*)XbH)[i] = 0u; ((u32*)XbL)[i] = 0u;
    }
    __syncthreads();

    // ---- single edge pass: dense count matrix only; X0 load in parallel ----
    for (int e = tid; e < EPG; e += 512) {
        int s = srcp[ebase + e] - base, d = dstp[ebase + e] - base;
        atomicAdd(&cnt[cn_idx(d, s)], 1.0f);
    }
    for (int i = tid; i < NPG * 16; i += 512) {
        int n = i >> 4, c4 = (i & 15) * 4;
        float4 v = *(const float4*)(nf + (size_t)(base + n) * F0 + c4);
        u32 h01, l01, h23, l23;
        split2(v.x, v.y, h01, l01);
        split2(v.z, v.w, h23, l23);
        int idx = xb_idx(n, c4);
        *(uint2*)&XbH[idx] = make_uint2(h01, h23);
        *(uint2*)&XbL[idx] = make_uint2(l01, l23);
    }
    __syncthreads();

    // ---- degrees from count matrix (exact; order-independent) + norms ----
    if (tid < 128) {
        int isOut = tid >> 6, n = tid & 63;
        if (n < NPG) {
            float s = 0.f;
            if (isOut) {
                for (int d = 0; d < NPG; ++d) s += cnt[cn_idx(d, n)];   // column sum
                nout64[n] = rsqrtf(fmaxf(s, 1.f));
            } else {
                for (int c = 0; c < 64; ++c) s += cnt[n * 64 + c];      // row sum (perm)
                nin64[n] = rsqrtf(fmaxf(s, 1.f));
            }
        } else {
            if (isOut) nout64[n] = 0.f; else nin64[n] = 0.f;
        }
    }
    __syncthreads();

    const int lane = tid & 63;
    const int nsg  = __builtin_amdgcn_readfirstlane(tid >> 6);
    const int l15  = lane & 15, lk = lane >> 4;

    // ---- A-fragments: exact counts -> bf16 registers (layer-invariant) ----
    short8 aReg[4][2];
#pragma unroll
    for (int ms = 0; ms < 4; ++ms) {
        const int d = ms * 16 + l15;
#pragma unroll
        for (int ks = 0; ks < 2; ++ks) {
            if (d < NPG) {
                int s0 = (ks * 32 + lk * 8) ^ ((d & 7) << 3);
                const float* cp = cnt + d * 64 + s0;
                float4 c0 = *(const float4*)cp;
                float4 c1 = *(const float4*)(cp + 4);
                uint4 q = make_uint4(cvtpk2(c0.x, c0.y), cvtpk2(c0.z, c0.w),
                                     cvtpk2(c1.x, c1.y), cvtpk2(c1.z, c1.w));
                aReg[ms][ks] = __builtin_bit_cast(short8, q);
            } else {
                uint4 z = make_uint4(0u, 0u, 0u, 0u);
                aReg[ms][ks] = __builtin_bit_cast(short8, z);
            }
        }
    }
    __syncthreads();

    layer_fn<2, false>(WpH, WpL, 0,  b0, XbH, XbL, aReg, pool, nin64, nout64, lane, nsg);
    __syncthreads();
    layer_fn<4, false>(WpH, WpL, 16, b1, XbH, XbL, aReg, pool, nin64, nout64, lane, nsg);
    __syncthreads();
    layer_fn<4, true >(WpH, WpL, 48, b2, XbH, XbL, aReg, pool, nin64, nout64, lane, nsg);
    __syncthreads();

    if (tid < FH) means[(size_t)g * FH + tid] = pool[tid] / (float)NPG;
}

// ---------------- Kernel 3: MLP head ----------------
__global__ __launch_bounds__(512) void mlp_head(
    const float* __restrict__ means, const float* __restrict__ Wp1,
    const float* __restrict__ bp1,   const float* __restrict__ Wp2,
    const float* __restrict__ bp2,   float* __restrict__ out)
{
    __shared__ float ms[8][FH];
    __shared__ float wred[8][8];
    const int tid = threadIdx.x;
    const int g0  = blockIdx.x * 8;

    for (int i = tid; i < 8 * FH; i += 512)
        ms[i >> 7][i & 127] = means[(size_t)g0 * FH + i];
    __syncthreads();

    const int f = tid;
    float acc[8];
    float bb = bp1[f];
#pragma unroll
    for (int gi = 0; gi < 8; ++gi) acc[gi] = bb;
    for (int k = 0; k < FH; ++k) {
        float w = Wp1[(size_t)k * FP + f];
#pragma unroll
        for (int gi = 0; gi < 8; ++gi) acc[gi] += ms[gi][k] * w;
    }
    float w2 = Wp2[f];
#pragma unroll
    for (int gi = 0; gi < 8; ++gi) {
        float v = fmaxf(acc[gi], 0.f) * w2;
#pragma unroll
        for (int o = 32; o > 0; o >>= 1) v += __shfl_down(v, o, 64);
        if ((tid & 63) == 0) wred[tid >> 6][gi] = v;
    }
    __syncthreads();
    if (tid < 8) {
        float s = 0.f;
#pragma unroll
        for (int w = 0; w < 8; ++w) s += wred[w][tid];
        out[g0 + tid] = s + bp2[0];
    }
}

extern "C" void kernel_launch(void* const* d_in, const int* in_sizes, int n_in,
                              void* d_out, int out_size, void* d_ws, size_t ws_size,
                              hipStream_t stream) {
    const float* nf   = (const float*)d_in[0];
    const int*   pair = (const int*)d_in[2];
    const float* W0  = (const float*)d_in[5];  const float* b0  = (const float*)d_in[6];
    const float* W1  = (const float*)d_in[7];  const float* b1  = (const float*)d_in[8];
    const float* W2  = (const float*)d_in[9];  const float* b2  = (const float*)d_in[10];
    const float* Wp1 = (const float*)d_in[11]; const float* bp1 = (const float*)d_in[12];
    const float* Wp2 = (const float*)d_in[13]; const float* bp2 = (const float*)d_in[14];

    float* means = (float*)d_ws;                                   // 1,024,000 B
    u16*   WpH   = (u16*)((char*)d_ws + (1 << 20));                // 81,920 B
    u16*   WpL   = (u16*)((char*)d_ws + (1 << 20) + 80 * 1024);    // 81,920 B
    float* out   = (float*)d_out;

    hipLaunchKernelGGL(pack_w, dim3(20), dim3(256), 0, stream, W0, W1, W2, WpH, WpL);
    hipLaunchKernelGGL(gcn_fused, dim3(NG), dim3(512), 0, stream,
                       nf, pair, b0, b1, b2, WpH, WpL, means);
    hipLaunchKernelGGL(mlp_head, dim3(NG / 8), dim3(512), 0, stream,
                       means, Wp1, bp1, Wp2, bp2, out);
}

// Round 18
// 91.259 us; speedup vs baseline: 1.2693x; 1.2693x over previous
//
#include <hip/hip_runtime.h>

#define NG   2000
#define NPG  50
#define EPG  800
#define F0   64
#define FH   128
#define FP   512

typedef __attribute__((ext_vector_type(8))) short  short8;
typedef __attribute__((ext_vector_type(8))) __bf16 bf16x8;
typedef __attribute__((ext_vector_type(4))) float  f32x4;
typedef unsigned short u16;
typedef unsigned int   u32;

__device__ inline u16 bf16_rne(float x) {
    u32 u = __builtin_bit_cast(u32, x);
    u += 0x7fffu + ((u >> 16) & 1u);
    return (u16)(u >> 16);
}
__device__ inline float bf16f(u16 h) {
    u32 u = ((u32)h) << 16;
    return __builtin_bit_cast(float, u);
}
// dst.b16[0] = bf16(src0), dst.b16[1] = bf16(src1)
__device__ inline u32 cvtpk2(float lo, float hi) {
    u32 r;
    asm("v_cvt_pk_bf16_f32 %0, %1, %2" : "=v"(r) : "v"(lo), "v"(hi));
    return r;
}
__device__ inline void split2(float v0, float v1, u32& hp, u32& lp) {
    hp = cvtpk2(v0, v1);
    float h0 = __builtin_bit_cast(float, hp << 16);
    float h1 = __builtin_bit_cast(float, hp & 0xffff0000u);
    lp = cvtpk2(v0 - h0, v1 - h1);
}
__device__ inline f32x4 mfma16(short8 a, short8 b, f32x4 c) {
    return __builtin_amdgcn_mfma_f32_16x16x32_bf16(
        __builtin_bit_cast(bf16x8, a), __builtin_bit_cast(bf16x8, b), c, 0, 0, 0);
}

// swizzled index helpers
__device__ inline int xb_idx(int row, int col) { return row * 128 + (col ^ ((row & 7) << 3)); } // u16 units
__device__ inline int cn_idx(int d, int s)     { return d * 64  + (s   ^ ((d   & 7) << 3)); }   // f32 units

// ---------- one-time W split+pack into MFMA B-fragment layout ----------
__global__ __launch_bounds__(256) void pack_w(
    const float* __restrict__ W0, const float* __restrict__ W1,
    const float* __restrict__ W2, u16* __restrict__ WpH, u16* __restrict__ WpL)
{
    int t = blockIdx.x * 256 + threadIdx.x;
    if (t >= 80 * 64) return;
    int fid = t >> 6, lane = t & 63;
    const float* W; int nsub, kstep;
    if (fid < 16)      { W = W0; int r = fid;      nsub = r >> 1; kstep = r & 1; }
    else if (fid < 48) { W = W1; int r = fid - 16; nsub = r >> 2; kstep = r & 3; }
    else               { W = W2; int r = fid - 48; nsub = r >> 2; kstep = r & 3; }
    int n  = nsub * 16 + (lane & 15);
    int kb = kstep * 32 + (lane >> 4) * 8;
    size_t off = (size_t)fid * 512 + (size_t)lane * 8;
#pragma unroll
    for (int i = 0; i < 8; ++i) {
        float v = W[(size_t)(kb + i) * FH + n];
        u16 h = bf16_rne(v);
        WpH[off + i] = h;
        WpL[off + i] = bf16_rne(v - bf16f(h));
    }
}

// ---------- fused layer, single-phase: mfma1 -> shuffle -> mfma2 (src->dst Xb) ----------
// wave = nsg owns feats [16*nsg, 16*nsg+16). NO internal barrier (Xb double-buffered).
template<int KST, bool LAST>
__device__ void layer_fn(const u16* __restrict__ WpH, const u16* __restrict__ WpL,
                         int fid0, const float* __restrict__ bias,
                         const u16* XsH, const u16* XsL,   // source Xb (read-only)
                         u16* XdH, u16* XdL,               // dest Xb (write)
                         const short8 (&aReg)[4][2],
                         float* pool, const float* nin64, const float* nout64,
                         int lane, int nsg)
{
    const int l15 = lane & 15, lk = lane >> 4;
    const int feat = nsg * 16 + l15;
    const float bc = bias[feat];

    // --- mfma1: T = (X @ W) * nout; T kept in registers (D-layout) ---
    f32x4 acc[4];
#pragma unroll
    for (int ms = 0; ms < 4; ++ms) acc[ms] = f32x4{0.f, 0.f, 0.f, 0.f};
#pragma unroll
    for (int ks = 0; ks < KST; ++ks) {
        size_t off = (size_t)(fid0 + nsg * KST + ks) * 512 + (size_t)lane * 8;
        short8 wwh = *(const short8*)(WpH + off);
        short8 wwl = *(const short8*)(WpL + off);
        const int c0 = ks * 32 + lk * 8;
#pragma unroll
        for (int ms = 0; ms < 4; ++ms) {
            const int arow = ms * 16 + l15;
            short8 xh = *(const short8*)&XsH[xb_idx(arow, c0)];
            short8 xl = *(const short8*)&XsL[xb_idx(arow, c0)];
            acc[ms] = mfma16(xh, wwh, acc[ms]);
            acc[ms] = mfma16(xh, wwl, acc[ms]);
            acc[ms] = mfma16(xl, wwh, acc[ms]);
        }
    }
    u32 Th01[4], Th23[4], Tl01[4], Tl23[4];
#pragma unroll
    for (int ms = 0; ms < 4; ++ms) {
        const int nb = ms * 16 + lk * 4;
        float4 nq = *(const float4*)&nout64[nb];   // 0 for nodes >= NPG
        split2(acc[ms][0] * nq.x, acc[ms][1] * nq.y, Th01[ms], Tl01[ms]);
        split2(acc[ms][2] * nq.z, acc[ms][3] * nq.w, Th23[ms], Tl23[ms]);
    }

    // --- in-wave redistribution: D-layout -> B-fragments (l15 preserved) ---
    // target (lk,i): node = ks*32+lk*8+i; src lane lk_s=(2lk+(i>>2))&3; ms=2ks+(lk>>1)
    const int srcA = (((lk << 1) & 3) << 4) | l15;
    const int srcB = srcA + 16;
    const bool hiMs = (lk & 2) != 0;
    short8 sbh[2], sbl[2];
#pragma unroll
    for (int ks = 0; ks < 2; ++ks) {
        u32 q0a = __shfl((int)Th01[2 * ks], srcA, 64), q0b = __shfl((int)Th01[2 * ks + 1], srcA, 64);
        u32 q1a = __shfl((int)Th23[2 * ks], srcA, 64), q1b = __shfl((int)Th23[2 * ks + 1], srcA, 64);
        u32 q2a = __shfl((int)Th01[2 * ks], srcB, 64), q2b = __shfl((int)Th01[2 * ks + 1], srcB, 64);
        u32 q3a = __shfl((int)Th23[2 * ks], srcB, 64), q3b = __shfl((int)Th23[2 * ks + 1], srcB, 64);
        uint4 qh = make_uint4(hiMs ? q0b : q0a, hiMs ? q1b : q1a,
                              hiMs ? q2b : q2a, hiMs ? q3b : q3a);
        u32 p0a = __shfl((int)Tl01[2 * ks], srcA, 64), p0b = __shfl((int)Tl01[2 * ks + 1], srcA, 64);
        u32 p1a = __shfl((int)Tl23[2 * ks], srcA, 64), p1b = __shfl((int)Tl23[2 * ks + 1], srcA, 64);
        u32 p2a = __shfl((int)Tl01[2 * ks], srcB, 64), p2b = __shfl((int)Tl01[2 * ks + 1], srcB, 64);
        u32 p3a = __shfl((int)Tl23[2 * ks], srcB, 64), p3b = __shfl((int)Tl23[2 * ks + 1], srcB, 64);
        uint4 ql = make_uint4(hiMs ? p0b : p0a, hiMs ? p1b : p1a,
                              hiMs ? p2b : p2a, hiMs ? p3b : p3a);
        sbh[ks] = __builtin_bit_cast(short8, qh);
        sbl[ks] = __builtin_bit_cast(short8, ql);
    }

    // --- mfma2: X'[dst] = relu((C @ T) * nin + b) ; writes DEST buffer (no barrier) ---
    float vs = 0.f;
#pragma unroll
    for (int ms = 0; ms < 4; ++ms) {
        f32x4 p0 = {0.f, 0.f, 0.f, 0.f}, p1 = p0;
        p0 = mfma16(aReg[ms][0], sbh[0], p0);
        p1 = mfma16(aReg[ms][1], sbh[1], p1);
        p0 = mfma16(aReg[ms][0], sbl[0], p0);
        p1 = mfma16(aReg[ms][1], sbl[1], p1);
        f32x4 a2 = p0 + p1;
        const int nb = ms * 16 + lk * 4;
        float4 ninq = *(const float4*)&nin64[nb];
        float v0 = (nb + 0 < NPG) ? fmaxf(fmaf(a2[0], ninq.x, bc), 0.f) : 0.f;
        float v1 = (nb + 1 < NPG) ? fmaxf(fmaf(a2[1], ninq.y, bc), 0.f) : 0.f;
        float v2 = (nb + 2 < NPG) ? fmaxf(fmaf(a2[2], ninq.z, bc), 0.f) : 0.f;
        float v3 = (nb + 3 < NPG) ? fmaxf(fmaf(a2[3], ninq.w, bc), 0.f) : 0.f;
        if (LAST) {
            vs += v0 + v1 + v2 + v3;
        } else {
            u32 hp01, lp01, hp23, lp23;
            split2(v0, v1, hp01, lp01);
            split2(v2, v3, hp23, lp23);
            XdH[xb_idx(nb + 0, feat)] = (u16)hp01;
            XdH[xb_idx(nb + 1, feat)] = (u16)(hp01 >> 16);
            XdH[xb_idx(nb + 2, feat)] = (u16)hp23;
            XdH[xb_idx(nb + 3, feat)] = (u16)(hp23 >> 16);
            XdL[xb_idx(nb + 0, feat)] = (u16)lp01;
            XdL[xb_idx(nb + 1, feat)] = (u16)(lp01 >> 16);
            XdL[xb_idx(nb + 2, feat)] = (u16)lp23;
            XdL[xb_idx(nb + 3, feat)] = (u16)(lp23 >> 16);
        }
    }
    if (LAST) {
        vs += __shfl_xor(vs, 16, 64);
        vs += __shfl_xor(vs, 32, 64);
        if (lane < 16) pool[feat] = vs;   // wave-exclusive feats: plain store
    }
}

// ---------- main fused kernel: one block = one graph; 6 barrier phases total ----------
__global__ __launch_bounds__(512, 2) void gcn_fused(
    const float* __restrict__ nf, const int* __restrict__ pair,
    const float* __restrict__ b0, const float* __restrict__ b1,
    const float* __restrict__ b2,
    const u16* __restrict__ WpH, const u16* __restrict__ WpL,
    float* __restrict__ means)
{
    __shared__ u16   XbH[2][64 * 128], XbL[2][64 * 128]; // double-buffered X hi/lo, swizzled
    __shared__ float cnt[NPG * 64];                      // exact edge counts (f32), swizzled
    __shared__ float pool[FH];
    __shared__ float nin64[64], nout64[64];

    const int tid  = threadIdx.x;
    const int g    = blockIdx.x;
    const int base = g * NPG, ebase = g * EPG;
    const int* srcp = pair;
    const int* dstp = pair + (size_t)NG * EPG;

    // ---- phase 1: init ----
    for (int i = tid; i < NPG * 64; i += 512) cnt[i] = 0.f;
    for (int i = 3200 + tid; i < 4096; i += 512) {   // Xb[0] pad rows 50-63
        ((u32*)XbH[0])[i] = 0u; ((u32*)XbL[0])[i] = 0u;
    }
    __syncthreads();

    // ---- phase 2: edge pass (count matrix) + X0 load/split into Xb[0] ----
    for (int e = tid; e < EPG; e += 512) {
        int s = srcp[ebase + e] - base, d = dstp[ebase + e] - base;
        atomicAdd(&cnt[cn_idx(d, s)], 1.0f);
    }
    for (int i = tid; i < NPG * 16; i += 512) {
        int n = i >> 4, c4 = (i & 15) * 4;
        float4 v = *(const float4*)(nf + (size_t)(base + n) * F0 + c4);
        u32 h01, l01, h23, l23;
        split2(v.x, v.y, h01, l01);
        split2(v.z, v.w, h23, l23);
        int idx = xb_idx(n, c4);
        *(uint2*)&XbH[0][idx] = make_uint2(h01, h23);
        *(uint2*)&XbL[0][idx] = make_uint2(l01, l23);
    }
    __syncthreads();

    const int lane = tid & 63;
    const int nsg  = __builtin_amdgcn_readfirstlane(tid >> 6);
    const int l15  = lane & 15, lk = lane >> 4;

    // ---- phase 3: norms (tid<128) + A-fragments (all threads; reads cnt only) ----
    if (tid < 128) {
        int isOut = tid >> 6, n = tid & 63;
        if (n < NPG) {
            float s = 0.f;
            if (isOut) {
                for (int d = 0; d < NPG; ++d) s += cnt[cn_idx(d, n)];   // column sum
                nout64[n] = rsqrtf(fmaxf(s, 1.f));
            } else {
                for (int c = 0; c < 64; ++c) s += cnt[n * 64 + c];      // row sum (perm)
                nin64[n] = rsqrtf(fmaxf(s, 1.f));
            }
        } else {
            if (isOut) nout64[n] = 0.f; else nin64[n] = 0.f;
        }
    }
    short8 aReg[4][2];
#pragma unroll
    for (int ms = 0; ms < 4; ++ms) {
        const int d = ms * 16 + l15;
#pragma unroll
        for (int ks = 0; ks < 2; ++ks) {
            if (d < NPG) {
                int s0 = (ks * 32 + lk * 8) ^ ((d & 7) << 3);
                const float* cp = cnt + d * 64 + s0;
                float4 c0 = *(const float4*)cp;
                float4 c1 = *(const float4*)(cp + 4);
                uint4 q = make_uint4(cvtpk2(c0.x, c0.y), cvtpk2(c0.z, c0.w),
                                     cvtpk2(c1.x, c1.y), cvtpk2(c1.z, c1.w));
                aReg[ms][ks] = __builtin_bit_cast(short8, q);
            } else {
                uint4 z = make_uint4(0u, 0u, 0u, 0u);
                aReg[ms][ks] = __builtin_bit_cast(short8, z);
            }
        }
    }
    __syncthreads();

    // ---- phases 4-6: one barrier per layer (Xb ping-pong) ----
    layer_fn<2, false>(WpH, WpL, 0,  b0, XbH[0], XbL[0], XbH[1], XbL[1],
                       aReg, pool, nin64, nout64, lane, nsg);
    __syncthreads();
    layer_fn<4, false>(WpH, WpL, 16, b1, XbH[1], XbL[1], XbH[0], XbL[0],
                       aReg, pool, nin64, nout64, lane, nsg);
    __syncthreads();
    layer_fn<4, true >(WpH, WpL, 48, b2, XbH[0], XbL[0], XbH[1], XbL[1],
                       aReg, pool, nin64, nout64, lane, nsg);
    __syncthreads();

    if (tid < FH) means[(size_t)g * FH + tid] = pool[tid] / (float)NPG;
}

// ---------------- Kernel 3: MLP head ----------------
__global__ __launch_bounds__(512) void mlp_head(
    const float* __restrict__ means, const float* __restrict__ Wp1,
    const float* __restrict__ bp1,   const float* __restrict__ Wp2,
    const float* __restrict__ bp2,   float* __restrict__ out)
{
    __shared__ float ms[8][FH];
    __shared__ float wred[8][8];
    const int tid = threadIdx.x;
    const int g0  = blockIdx.x * 8;

    for (int i = tid; i < 8 * FH; i += 512)
        ms[i >> 7][i & 127] = means[(size_t)g0 * FH + i];
    __syncthreads();

    const int f = tid;
    float acc[8];
    float bb = bp1[f];
#pragma unroll
    for (int gi = 0; gi < 8; ++gi) acc[gi] = bb;
    for (int k = 0; k < FH; ++k) {
        float w = Wp1[(size_t)k * FP + f];
#pragma unroll
        for (int gi = 0; gi < 8; ++gi) acc[gi] += ms[gi][k] * w;
    }
    float w2 = Wp2[f];
#pragma unroll
    for (int gi = 0; gi < 8; ++gi) {
        float v = fmaxf(acc[gi], 0.f) * w2;
#pragma unroll
        for (int o = 32; o > 0; o >>= 1) v += __shfl_down(v, o, 64);
        if ((tid & 63) == 0) wred[tid >> 6][gi] = v;
    }
    __syncthreads();
    if (tid < 8) {
        float s = 0.f;
#pragma unroll
        for (int w = 0; w < 8; ++w) s += wred[w][tid];
        out[g0 + tid] = s + bp2[0];
    }
}

extern "C" void kernel_launch(void* const* d_in, const int* in_sizes, int n_in,
                              void* d_out, int out_size, void* d_ws, size_t ws_size,
                              hipStream_t stream) {
    const float* nf   = (const float*)d_in[0];
    const int*   pair = (const int*)d_in[2];
    const float* W0  = (const float*)d_in[5];  const float* b0  = (const float*)d_in[6];
    const float* W1  = (const float*)d_in[7];  const float* b1  = (const float*)d_in[8];
    const float* W2  = (const float*)d_in[9];  const float* b2  = (const float*)d_in[10];
    const float* Wp1 = (const float*)d_in[11]; const float* bp1 = (const float*)d_in[12];
    const float* Wp2 = (const float*)d_in[13]; const float* bp2 = (const float*)d_in[14];

    float* means = (float*)d_ws;                                   // 1,024,000 B
    u16*   WpH   = (u16*)((char*)d_ws + (1 << 20));                // 81,920 B
    u16*   WpL   = (u16*)((char*)d_ws + (1 << 20) + 80 * 1024);    // 81,920 B
    float* out   = (float*)d_out;

    hipLaunchKernelGGL(pack_w, dim3(20), dim3(256), 0, stream, W0, W1, W2, WpH, WpL);
    hipLaunchKernelGGL(gcn_fused, dim3(NG), dim3(512), 0, stream,
                       nf, pair, b0, b1, b2, WpH, WpL, means);
    hipLaunchKernelGGL(mlp_head, dim3(NG / 8), dim3(512), 0, stream,
                       means, Wp1, bp1, Wp2, bp2, out);
}